// Round 22
// baseline (435.732 us; speedup 1.0000x reference)
//
#include <hip/hip_runtime.h>
#include <hip/hip_bf16.h>
#include <stdint.h>

// Problem dims (fixed by reference)
#define Bq    8192
#define Hh    8
#define Dd    16
#define Kk    16
#define Nn    4096
#define DFf   16
#define ROWS  (Bq*Hh)          // 65536
#define COLS  (Dd*Kk)          // 256
#define EPSF  1e-6f

typedef unsigned long long u64;
typedef unsigned int u32;
typedef __attribute__((ext_vector_type(8)))  short bf16x8;
typedef __attribute__((ext_vector_type(16))) float f32x16;

// async global->LDS, 16B per lane; LDS dest = wave-uniform base + lane*16
#define GLOAD_LDS(g, l) __builtin_amdgcn_global_load_lds( \
    (const __attribute__((address_space(1))) u32*)(g), \
    (__attribute__((address_space(3))) u32*)(l), 16, 0, 0)

// ---------- helpers ----------
__device__ __forceinline__ float dot4(float4 a, float4 b) {
    return fmaf(a.x, b.x, fmaf(a.y, b.y, fmaf(a.z, b.z, a.w * b.w)));
}
__device__ __forceinline__ float wave_sum(float v) {
    #pragma unroll
    for (int m = 32; m > 0; m >>= 1) v += __shfl_xor(v, m, 64);
    return v;
}
__device__ __forceinline__ u32 f32_sortable(float f) {
    u32 u = __float_as_uint(f);
    return (u & 0x80000000u) ? ~u : (u | 0x80000000u);
}
// pack 2 floats -> 2 bf16 (RNE); low 16 bits = a
__device__ __forceinline__ u32 pk2(float a, float b) {
    union { __hip_bfloat162 h; u32 u; } v;
    v.h = __float22bfloat162_rn(make_float2(a, b));
    return v.u;
}
// exact fp32 rerank, R2's accepted expression tree (sequential fmaf over 64 float4s)
__device__ __forceinline__ void exact_rerank(const float* __restrict__ X,
                                             const float* __restrict__ CB,
                                             const float* __restrict__ xx,
                                             const float* __restrict__ cbn,
                                             int row, int col,
                                             u64* __restrict__ best) {
    const float4* xp = (const float4*)(X + (size_t)row * COLS);
    const float4* cp = (const float4*)(CB + (size_t)col * COLS);
    float d = 0.f;
    #pragma unroll 8
    for (int q = 0; q < 64; ++q) {
        float4 a = xp[q], b = cp[q];
        d = fmaf(a.x, b.x, d); d = fmaf(a.y, b.y, d);
        d = fmaf(a.z, b.z, d); d = fmaf(a.w, b.w, d);
    }
    float d2e = fmaf(-2.f, d, xx[row]) + cbn[col];
    u64 pk = ((u64)f32_sortable(d2e) << 32) | (u32)col;
    atomicMin(&best[row], pk);
}

// ---------- kernel 0: xx[r], X->bf16 (row-major), init best ----------
__global__ __launch_bounds__(256) void k_prep(const float* __restrict__ X,
                                              short* __restrict__ Xh,
                                              float* __restrict__ xx,
                                              u64* __restrict__ best) {
    int r    = blockIdx.x * 4 + (threadIdx.x >> 6);
    int lane = threadIdx.x & 63;
    float4 v = *reinterpret_cast<const float4*>(X + (size_t)r * COLS + lane * 4);
    uint2 p; p.x = pk2(v.x, v.y); p.y = pk2(v.z, v.w);
    *reinterpret_cast<uint2*>(Xh + (size_t)r * COLS + lane * 4) = p;
    float s = wave_sum(v.x*v.x + v.y*v.y + v.z*v.z + v.w*v.w);
    if (lane == 0) { xx[r] = s; best[r] = ~0ull; }
}

// ---------- kernel 1: codebook fp32 + 32x32-FRAGMENT bf16 + cbn (+acc-order copy) ----------
// CBf layout (R10/R13, HW-verified): per 32-code tile (16 KB), frag f = kstep
// (0..15) is 1 KB: lane l = h*32 + c holds code row (tile*32 + c),
// k = kstep*16 + h*8 .. +8.  cbn_f = cbn permuted into acc order.
__global__ __launch_bounds__(256) void k_codebook(const float* __restrict__ fc,
                                                  const float* __restrict__ Wi,
                                                  const float* __restrict__ Wo,
                                                  float* __restrict__ CB,
                                                  short* __restrict__ CBf,
                                                  float* __restrict__ cbn,
                                                  float* __restrict__ cbn_f) {
    int n = blockIdx.x, tid = threadIdx.x;
    int o = tid >> 4, k = tid & 15;
    __shared__ float fcs[256], wis[256], wos[256], hs[256], sq[256];
    __shared__ short cvs_sh[256];
    fcs[tid] = fc[(size_t)n * 256 + tid];
    wis[tid] = Wi[tid];
    wos[tid] = Wo[tid];
    __syncthreads();
    float hp = 0.f;
    #pragma unroll
    for (int i = 0; i < 16; ++i) hp = fmaf(wis[o*16 + i], fcs[i*16 + k], hp);
    hs[tid] = hp;
    __syncthreads();
    float h0 = hs[o * 16];
    float x3 = h0 * h0 * h0;
    float inner = 0.7978845608028654f * fmaf(0.044715f, x3, h0);
    float g = 0.5f * h0 * (1.f + tanhf(inner));
    float hg = hp * g;
    __syncthreads();
    hs[tid] = hg;
    __syncthreads();
    float cv = 0.f;
    #pragma unroll
    for (int i = 0; i < 16; ++i) cv = fmaf(wos[o*16 + i], hs[i*16 + k], cv);
    CB[(size_t)n * 256 + tid] = cv;
    { union { __hip_bfloat16 h; short s; } c; c.h = __float2bfloat16(cv);
      cvs_sh[tid] = c.s; }
    sq[tid] = cv * cv;
    __syncthreads();
    #pragma unroll
    for (int st = 128; st > 0; st >>= 1) {
        if (tid < st) sq[tid] += sq[tid + st];
        __syncthreads();
    }
    if (tid == 0) {
        cbn[n] = sq[0];
        int tile = n >> 5, c = n & 31;
        int h = (c >> 2) & 1, r = (c & 3) | ((c >> 3) << 2);
        cbn_f[tile * 32 + h * 16 + r] = sq[0];
    }
    // swizzled write: 32 chunks of 8 bf16 -> 32x32-fragment slots
    if (tid < 32) {
        int kc = tid;                      // 8-short chunk, k = kc*8
        int tile = n >> 5, c = n & 31;
        int kstep = kc >> 1, h = kc & 1;
        size_t off = (size_t)tile * 8192 + kstep * 512 + h * 256 + c * 8;
        *reinterpret_cast<uint4*>(CBf + off) =
            *reinterpret_cast<const uint4*>(&cvs_sh[kc * 8]);
    }
}

// ---------- kernel 1b: single-block max(cbn) -> cbn_max (plain store) ----------
__global__ __launch_bounds__(256) void k_reduce_cbn(const float* __restrict__ cbn,
                                                    u32* __restrict__ cbn_max) {
    __shared__ float sn[256];
    int tid = threadIdx.x;
    float cm = 0.f;
    for (int i = tid; i < Nn; i += 256) cm = fmaxf(cm, cbn[i]);
    sn[tid] = cm;
    __syncthreads();
    #pragma unroll
    for (int st = 128; st > 0; st >>= 1) {
        if (tid < st) sn[tid] = fmaxf(sn[tid], sn[tid + st]);
        __syncthreads();
    }
    if (tid == 0) *cbn_max = __float_as_uint(sn[0]);
}

// ---------- kernel 2: DUAL-ROW-BLOCK swapped-operand 32x32 screen ----------
// 512 blocks x 256 threads: band = bid>>1 (256 x-rows: 4 waves x 64), half =
// bid&1 (2048 codes = 64 tiles). KEY CHANGE vs R16: each wave owns TWO
// 32-row blocks (rows w*64+cl and +32); ONE code-fragment LDS read feeds
// BOTH MFMA chains -> LDS bytes/output HALVED (16 -> 8 B), same 32 MFMA/step
// as R16's pair but on half the LDS reads, with 2-chain ILP. Same output
// coverage (256 rows x 2048 codes = R16's 128 x 4096 per block).
// LDS = 2x16KB double buffer ONLY (cbn_f from global, L2-hot, R21-validated).
// Single-barrier 2-phase: wait vmcnt(0); barrier; STAGE(t+1 -> other buf);
// 16 ds_read_b128 + 32 MFMA; EPI A + EPI B (register-only, 1 shfl each).
// 6-slot stale-eviction candidates PER row-block (R15-proven). Partial-sweep
// safety (R11): running rmin includes current tile -> true argmin + exact
// ties enter some block's set; exact fp32 rerank + packed atomicMin merges.
// Regs ~220 < 256 @ launch_bounds(256,2) (no forced cap; WRITE_SIZE tripwire).
__global__ __launch_bounds__(256, 2) void k_screen_fused(
        const short* __restrict__ Xh,
        const short* __restrict__ CBf,
        const float* __restrict__ X,
        const float* __restrict__ CB,
        const float* __restrict__ cbn,
        const float* __restrict__ cbn_f,
        const float* __restrict__ xx,
        u64* __restrict__ best,
        const u32* __restrict__ cbn_max) {
    __shared__ __align__(16) short Bs[2][8192];   // 2 x 16 KB code tiles ONLY

    const int tid  = threadIdx.x;
    const int lane = tid & 63;
    const int w    = tid >> 6;           // wave 0..3
    const int cl   = lane & 31;
    const int kh   = lane >> 5;          // k-half / code-half
    const int half = blockIdx.x & 1;     // codebook half
    const int tgBase = half * 64;        // first global tile of this half
    const int bmBase = (blockIdx.x >> 1) * 256;   // 64 x-rows per wave
    const int myrowA = bmBase + w * 64 + cl;
    const int myrowB = myrowA + 32;

// stage GLOBAL tile tg into Bs[buf]: 4 gloads/thread
#define STAGE(tg_, buf) do { \
        int _t = (tg_); \
        _Pragma("unroll") \
        for (int _i = 0; _i < 4; ++_i) { \
            int _f = _i * 4 + w; \
            const short* _g = CBf + (size_t)_t * 8192 + _f * 512 + lane * 8; \
            GLOAD_LDS(_g, &Bs[(buf)][_f * 512]); \
        } \
    } while (0)

    // X fragments (B-operand) for BOTH row-blocks: 128 VGPR
    bf16x8 afA[16], afB[16];
    {
        const short* apA = Xh + ((size_t)myrowA << 8) + kh * 8;
        const short* apB = Xh + ((size_t)myrowB << 8) + kh * 8;
        #pragma unroll
        for (int ks = 0; ks < 16; ++ks) {
            afA[ks] = *reinterpret_cast<const bf16x8*>(apA + ks * 16);
            afB[ks] = *reinterpret_cast<const bf16x8*>(apB + ks * 16);
        }
    }

    // lane-local threshold slack (exact per-row, R16 formula)
    float dltA, dltB, rminA = 1e30f, rminB = 1e30f;
    {
        float cm = __uint_as_float(*cbn_max);
        dltA = fmaf(0.003f, sqrtf(xx[myrowA] * cm), 0.01f);
        dltB = fmaf(0.003f, sqrtf(xx[myrowB] * cm), 0.01f);
    }

    STAGE(tgBase, 0);           // prologue: 4 issues/thread outstanding

    // 6 candidate slots per row-block (registers, static indexing)
    float ga0 = 1e30f, ga1 = 1e30f, ga2 = 1e30f, ga3 = 1e30f, ga4 = 1e30f, ga5 = 1e30f;
    u32   sa0 = 0,     sa1 = 0,     sa2 = 0,     sa3 = 0,     sa4 = 0,     sa5 = 0;
    float gb0 = 1e30f, gb1 = 1e30f, gb2 = 1e30f, gb3 = 1e30f, gb4 = 1e30f, gb5 = 1e30f;
    u32   sb0 = 0,     sb1 = 0,     sb2 = 0,     sb3 = 0,     sb4 = 0,     sb5 = 0;

// per-tile, per-row-block epilogue + candidate insert (register-only, 1 shfl)
#define EPI(accv, rmin_, dlt_, myrow_, g0,g1,g2,g3,g4,g5, s0,s1,s2,s3,s4,s5) do { \
        float gv[16], _m = 1e30f; \
        _Pragma("unroll") \
        for (int _r = 0; _r < 16; ++_r) { \
            gv[_r] = fmaf(-2.f, (accv)[_r], cbnv[_r]); \
            _m = fminf(_m, gv[_r]); \
        } \
        _m = fminf(_m, __shfl_xor(_m, 32, 64)); \
        rmin_ = fminf(rmin_, _m); \
        float _thr = rmin_ + dlt_; \
        _Pragma("unroll") \
        for (int _r = 0; _r < 16; ++_r) { \
            if (gv[_r] <= _thr) { \
                u32 _code = (u32)((tgBase + t) * 32 + (_r & 3) + 8 * (_r >> 2) + 4 * kh); \
                float _mg = g0; int _mi = 0; \
                if (g1 > _mg) { _mg = g1; _mi = 1; } \
                if (g2 > _mg) { _mg = g2; _mi = 2; } \
                if (g3 > _mg) { _mg = g3; _mi = 3; } \
                if (g4 > _mg) { _mg = g4; _mi = 4; } \
                if (g5 > _mg) { _mg = g5; _mi = 5; } \
                if (_mg > _thr) { \
                    if      (_mi == 0) { g0 = gv[_r]; s0 = _code; } \
                    else if (_mi == 1) { g1 = gv[_r]; s1 = _code; } \
                    else if (_mi == 2) { g2 = gv[_r]; s2 = _code; } \
                    else if (_mi == 3) { g3 = gv[_r]; s3 = _code; } \
                    else if (_mi == 4) { g4 = gv[_r]; s4 = _code; } \
                    else               { g5 = gv[_r]; s5 = _code; } \
                } else { \
                    exact_rerank(X, CB, xx, cbn, myrow_, (int)_code, best); \
                } \
            } \
        } \
    } while (0)

    for (int t = 0; t < 64; ++t) {          // 64 single-tile steps, 1 barrier each
        asm volatile("s_waitcnt vmcnt(0)" ::: "memory");   // stage(t) landed
        __builtin_amdgcn_sched_barrier(0);
        __builtin_amdgcn_s_barrier();       // all loads landed + buf[(t+1)&1] free
        __builtin_amdgcn_sched_barrier(0);

        STAGE(tgBase + ((t + 1) & 63), (t + 1) & 1);  // next tile flies under compute

        // cbn values for this tile from GLOBAL (L2-hot, shared by A and B)
        float cbnv[16];
        #pragma unroll
        for (int q = 0; q < 4; ++q)
            *reinterpret_cast<float4*>(&cbnv[q * 4]) =
                *reinterpret_cast<const float4*>(
                    &cbn_f[(tgBase + t) * 32 + kh * 16 + q * 4]);

        f32x16 aA, aB;
        #pragma unroll
        for (int r = 0; r < 16; ++r) { aA[r] = 0.f; aB[r] = 0.f; }

        const short* Bt = &Bs[t & 1][0];
        #pragma unroll
        for (int ks = 0; ks < 16; ++ks) {   // ONE cf read feeds BOTH chains
            bf16x8 cf = *reinterpret_cast<const bf16x8*>(&Bt[ks * 512 + lane * 8]);
            aA = __builtin_amdgcn_mfma_f32_32x32x16_bf16(cf, afA[ks], aA, 0, 0, 0);
            aB = __builtin_amdgcn_mfma_f32_32x32x16_bf16(cf, afB[ks], aB, 0, 0, 0);
        }

        EPI(aA, rminA, dltA, myrowA, ga0,ga1,ga2,ga3,ga4,ga5, sa0,sa1,sa2,sa3,sa4,sa5);
        EPI(aB, rminB, dltB, myrowB, gb0,gb1,gb2,gb3,gb4,gb5, sb0,sb1,sb2,sb3,sb4,sb5);
    }

    // post-loop: exact fp32 rerank of slots still within each FINAL window
    float thrA = rminA + dltA, thrB = rminB + dltB;
    if (ga0 <= thrA) exact_rerank(X, CB, xx, cbn, myrowA, (int)sa0, best);
    if (ga1 <= thrA) exact_rerank(X, CB, xx, cbn, myrowA, (int)sa1, best);
    if (ga2 <= thrA) exact_rerank(X, CB, xx, cbn, myrowA, (int)sa2, best);
    if (ga3 <= thrA) exact_rerank(X, CB, xx, cbn, myrowA, (int)sa3, best);
    if (ga4 <= thrA) exact_rerank(X, CB, xx, cbn, myrowA, (int)sa4, best);
    if (ga5 <= thrA) exact_rerank(X, CB, xx, cbn, myrowA, (int)sa5, best);
    if (gb0 <= thrB) exact_rerank(X, CB, xx, cbn, myrowB, (int)sb0, best);
    if (gb1 <= thrB) exact_rerank(X, CB, xx, cbn, myrowB, (int)sb1, best);
    if (gb2 <= thrB) exact_rerank(X, CB, xx, cbn, myrowB, (int)sb2, best);
    if (gb3 <= thrB) exact_rerank(X, CB, xx, cbn, myrowB, (int)sb3, best);
    if (gb4 <= thrB) exact_rerank(X, CB, xx, cbn, myrowB, (int)sb4, best);
    if (gb5 <= thrB) exact_rerank(X, CB, xx, cbn, myrowB, (int)sb5, best);
#undef EPI
#undef STAGE
}

// ---------- kernel 3: gather e, Householder STE ----------
__global__ __launch_bounds__(256) void k_epilogue(const float* __restrict__ X,
                                                  const float* __restrict__ CB,
                                                  const u64* __restrict__ best,
                                                  float* __restrict__ Eout,
                                                  float* __restrict__ Sout) {
    int r    = blockIdx.x * 4 + (threadIdx.x >> 6);
    int lane = threadIdx.x & 63;
    int idx  = (int)(best[r] & 0xffffffffull);

    float4 xv = *reinterpret_cast<const float4*>(X  + (size_t)r   * COLS + lane * 4);
    float4 ev = *reinterpret_cast<const float4*>(CB + (size_t)idx * COLS + lane * 4);

    float xn2 = wave_sum(dot4(xv, xv));
    float en2 = wave_sum(dot4(ev, ev));
    float xn = sqrtf(xn2), en = sqrtf(en2);
    float invx = 1.f / fmaxf(xn, EPSF);
    float inve = 1.f / fmaxf(en, EPSF);

    float4 xd, ed, sd0;
    xd.x = xv.x*invx; xd.y = xv.y*invx; xd.z = xv.z*invx; xd.w = xv.w*invx;
    ed.x = ev.x*inve; ed.y = ev.y*inve; ed.z = ev.z*inve; ed.w = ev.w*inve;
    sd0.x = xd.x+ed.x; sd0.y = xd.y+ed.y; sd0.z = xd.z+ed.z; sd0.w = xd.w+ed.w;

    float sdn2 = wave_sum(dot4(sd0, sd0));
    float p1   = wave_sum(dot4(sd0, xv));
    float p2   = wave_sum(dot4(xd,  xv));
    float invs = 1.f / fmaxf(sqrtf(sdn2), EPSF);

    float csd = -2.f * invs * invs * p1;
    float ced =  2.f * p2;
    float4 rr;
    rr.x = fmaf(csd, sd0.x, fmaf(ced, ed.x, xv.x));
    rr.y = fmaf(csd, sd0.y, fmaf(ced, ed.y, xv.y));
    rr.z = fmaf(csd, sd0.z, fmaf(ced, ed.z, xv.z));
    rr.w = fmaf(csd, sd0.w, fmaf(ced, ed.w, xv.w));
    float sc = en * invx;
    float4 sv; sv.x = rr.x*sc; sv.y = rr.y*sc; sv.z = rr.z*sc; sv.w = rr.w*sc;

    *reinterpret_cast<float4*>(Eout + (size_t)r * COLS + lane * 4) = ev;
    *reinterpret_cast<float4*>(Sout + (size_t)r * COLS + lane * 4) = sv;
}

// ---------- launcher ----------
extern "C" void kernel_launch(void* const* d_in, const int* in_sizes, int n_in,
                              void* d_out, int out_size, void* d_ws, size_t ws_size,
                              hipStream_t stream) {
    const float* x  = (const float*)d_in[0];
    const float* fc = (const float*)d_in[1];
    const float* Wi = (const float*)d_in[2];
    const float* Wo = (const float*)d_in[3];

    // ws layout (~5 MB)
    char* ws = (char*)d_ws;
    u64*   best    = (u64*)ws;                            ws += (size_t)ROWS * 8;
    float* CBws    = (float*)ws;                          ws += (size_t)Nn * COLS * 4;
    float* cbn     = (float*)ws;                          ws += (size_t)Nn * 4;
    float* cbn_f   = (float*)ws;                          ws += (size_t)Nn * 4;
    float* xx      = (float*)ws;                          ws += (size_t)ROWS * 4;
    u32*   cbn_max = (u32*)ws;

    // bf16 copies live in d_out (128 MiB), only overwritten by k_epilogue at
    // the very end: Xh = 32 MiB at offset 0, CBf = 2 MiB at offset 64 MiB.
    short* Xh  = (short*)d_out;
    short* CBf = (short*)((char*)d_out + (64u << 20));

    float* Eout = (float*)d_out;
    float* Sout = Eout + (size_t)ROWS * COLS;

    k_prep<<<ROWS / 4, 256, 0, stream>>>(x, Xh, xx, best);
    k_codebook<<<Nn, 256, 0, stream>>>(fc, Wi, Wo, CBws, CBf, cbn, cbn_f);
    k_reduce_cbn<<<1, 256, 0, stream>>>(cbn, cbn_max);
    k_screen_fused<<<(ROWS / 256) * 2, 256, 0, stream>>>(Xh, CBf, x, CBws, cbn,
                                                         cbn_f, xx, best, cbn_max);
    k_epilogue<<<ROWS / 4, 256, 0, stream>>>(x, CBws, best, Eout, Sout);
}

// Round 23
// 284.835 us; speedup vs baseline: 1.5298x; 1.5298x over previous
//
#include <hip/hip_runtime.h>
#include <hip/hip_bf16.h>
#include <stdint.h>

// Problem dims (fixed by reference)
#define Bq    8192
#define Hh    8
#define Dd    16
#define Kk    16
#define Nn    4096
#define DFf   16
#define ROWS  (Bq*Hh)          // 65536
#define COLS  (Dd*Kk)          // 256
#define EPSF  1e-6f

typedef unsigned long long u64;
typedef unsigned int u32;
typedef __attribute__((ext_vector_type(8)))  short bf16x8;
typedef __attribute__((ext_vector_type(16))) float f32x16;

// async global->LDS, 16B per lane; LDS dest = wave-uniform base + lane*16
#define GLOAD_LDS(g, l) __builtin_amdgcn_global_load_lds( \
    (const __attribute__((address_space(1))) u32*)(g), \
    (__attribute__((address_space(3))) u32*)(l), 16, 0, 0)

// ---------- helpers ----------
__device__ __forceinline__ float dot4(float4 a, float4 b) {
    return fmaf(a.x, b.x, fmaf(a.y, b.y, fmaf(a.z, b.z, a.w * b.w)));
}
__device__ __forceinline__ float wave_sum(float v) {
    #pragma unroll
    for (int m = 32; m > 0; m >>= 1) v += __shfl_xor(v, m, 64);
    return v;
}
__device__ __forceinline__ u32 f32_sortable(float f) {
    u32 u = __float_as_uint(f);
    return (u & 0x80000000u) ? ~u : (u | 0x80000000u);
}
// pack 2 floats -> 2 bf16 (RNE); low 16 bits = a
__device__ __forceinline__ u32 pk2(float a, float b) {
    union { __hip_bfloat162 h; u32 u; } v;
    v.h = __float22bfloat162_rn(make_float2(a, b));
    return v.u;
}
// exact fp32 rerank, R2's accepted expression tree (sequential fmaf over 64 float4s)
__device__ __forceinline__ void exact_rerank(const float* __restrict__ X,
                                             const float* __restrict__ CB,
                                             const float* __restrict__ xx,
                                             const float* __restrict__ cbn,
                                             int row, int col,
                                             u64* __restrict__ best) {
    const float4* xp = (const float4*)(X + (size_t)row * COLS);
    const float4* cp = (const float4*)(CB + (size_t)col * COLS);
    float d = 0.f;
    #pragma unroll 8
    for (int q = 0; q < 64; ++q) {
        float4 a = xp[q], b = cp[q];
        d = fmaf(a.x, b.x, d); d = fmaf(a.y, b.y, d);
        d = fmaf(a.z, b.z, d); d = fmaf(a.w, b.w, d);
    }
    float d2e = fmaf(-2.f, d, xx[row]) + cbn[col];
    u64 pk = ((u64)f32_sortable(d2e) << 32) | (u32)col;
    atomicMin(&best[row], pk);
}

// ---------- kernel 0: xx[r], X->bf16 (row-major), init best (NO atomics) ----------
__global__ __launch_bounds__(256) void k_prep(const float* __restrict__ X,
                                              short* __restrict__ Xh,
                                              float* __restrict__ xx,
                                              u64* __restrict__ best) {
    int r    = blockIdx.x * 4 + (threadIdx.x >> 6);
    int lane = threadIdx.x & 63;
    float4 v = *reinterpret_cast<const float4*>(X + (size_t)r * COLS + lane * 4);
    uint2 p; p.x = pk2(v.x, v.y); p.y = pk2(v.z, v.w);
    *reinterpret_cast<uint2*>(Xh + (size_t)r * COLS + lane * 4) = p;
    float s = wave_sum(v.x*v.x + v.y*v.y + v.z*v.z + v.w*v.w);
    if (lane == 0) { xx[r] = s; best[r] = ~0ull; }
}

// ---------- kernel 1: codebook fp32 + 32x32-FRAGMENT bf16 + cbn (+acc-order copy) ----------
// CBf layout (R10/R13, HW-verified): per 32-code tile (16 KB), frag f = kstep
// (0..15) is 1 KB: lane l = h*32 + c holds code row (tile*32 + c),
// k = kstep*16 + h*8 .. +8.  cbn_f = cbn permuted into acc order:
// cbn_f[tile*32 + h*16 + r] = cbn[tile*32 + crow(r,h)], crow = (r&3)+8*(r>>2)+4h.
// NO single-address atomics (R19 lesson): cbn_max computed by k_reduce_cbn.
__global__ __launch_bounds__(256) void k_codebook(const float* __restrict__ fc,
                                                  const float* __restrict__ Wi,
                                                  const float* __restrict__ Wo,
                                                  float* __restrict__ CB,
                                                  short* __restrict__ CBf,
                                                  float* __restrict__ cbn,
                                                  float* __restrict__ cbn_f) {
    int n = blockIdx.x, tid = threadIdx.x;
    int o = tid >> 4, k = tid & 15;
    __shared__ float fcs[256], wis[256], wos[256], hs[256], sq[256];
    __shared__ short cvs_sh[256];
    fcs[tid] = fc[(size_t)n * 256 + tid];
    wis[tid] = Wi[tid];
    wos[tid] = Wo[tid];
    __syncthreads();
    float hp = 0.f;
    #pragma unroll
    for (int i = 0; i < 16; ++i) hp = fmaf(wis[o*16 + i], fcs[i*16 + k], hp);
    hs[tid] = hp;
    __syncthreads();
    float h0 = hs[o * 16];
    float x3 = h0 * h0 * h0;
    float inner = 0.7978845608028654f * fmaf(0.044715f, x3, h0);
    float g = 0.5f * h0 * (1.f + tanhf(inner));
    float hg = hp * g;
    __syncthreads();
    hs[tid] = hg;
    __syncthreads();
    float cv = 0.f;
    #pragma unroll
    for (int i = 0; i < 16; ++i) cv = fmaf(wos[o*16 + i], hs[i*16 + k], cv);
    CB[(size_t)n * 256 + tid] = cv;
    { union { __hip_bfloat16 h; short s; } c; c.h = __float2bfloat16(cv);
      cvs_sh[tid] = c.s; }
    sq[tid] = cv * cv;
    __syncthreads();
    #pragma unroll
    for (int st = 128; st > 0; st >>= 1) {
        if (tid < st) sq[tid] += sq[tid + st];
        __syncthreads();
    }
    if (tid == 0) {
        cbn[n] = sq[0];
        int tile = n >> 5, c = n & 31;
        int h = (c >> 2) & 1, r = (c & 3) | ((c >> 3) << 2);
        cbn_f[tile * 32 + h * 16 + r] = sq[0];
    }
    // swizzled write: 32 chunks of 8 bf16 -> 32x32-fragment slots
    if (tid < 32) {
        int kc = tid;                      // 8-short chunk, k = kc*8
        int tile = n >> 5, c = n & 31;
        int kstep = kc >> 1, h = kc & 1;
        size_t off = (size_t)tile * 8192 + kstep * 512 + h * 256 + c * 8;
        *reinterpret_cast<uint4*>(CBf + off) =
            *reinterpret_cast<const uint4*>(&cvs_sh[kc * 8]);
    }
}

// ---------- kernel 1b: single-block max(cbn) -> cbn_max (plain store) ----------
__global__ __launch_bounds__(256) void k_reduce_cbn(const float* __restrict__ cbn,
                                                    u32* __restrict__ cbn_max) {
    __shared__ float sn[256];
    int tid = threadIdx.x;
    float cm = 0.f;
    for (int i = tid; i < Nn; i += 256) cm = fmaxf(cm, cbn[i]);
    sn[tid] = cm;
    __syncthreads();
    #pragma unroll
    for (int st = 128; st > 0; st >>= 1) {
        if (tid < st) sn[tid] = fmaxf(sn[tid], sn[tid + st]);
        __syncthreads();
    }
    if (tid == 0) *cbn_max = __float_as_uint(sn[0]);
}

// ---------- kernel 2: R16 screen VERBATIM (best measured: 251 us) ----------
// 512 blocks x 256 threads (4 waves x 32 x-rows), swapped-operand 32x32:
// lane owns one x-row; mfma(code_frag, x_frag); register-only EPI + 1 shfl
// per tile; 6-slot stale-eviction candidates. Pair of 16 KB tiles per step
// through a DOUBLE 32 KB buffer (two independent 16-deep MFMA chains);
// two-barrier counted-vmcnt schedule: wait vmcnt(8); barrier A; 32
// ds_read_b128 + 32 MFMA + 2 EPIs; barrier B; STAGE2(pair s+2, buf s&1).
// Candidate safety: rmin only decreases -> argmin + exact ties never
// evicted; exact fp32 rerank (R2 tree) + packed atomicMin merges.
__global__ __launch_bounds__(256, 2) void k_screen_fused(
        const short* __restrict__ Xh,
        const short* __restrict__ CBf,
        const float* __restrict__ X,
        const float* __restrict__ CB,
        const float* __restrict__ cbn,
        const float* __restrict__ cbn_f,
        const float* __restrict__ xx,
        u64* __restrict__ best,
        const u32* __restrict__ cbn_max) {
    __shared__ __align__(16) short Bs[2][16384];  // 2 x 32 KB tile pairs
    __shared__ float cbn_fs[Nn];                  // 16 KB, acc-order

    const int tid  = threadIdx.x;
    const int lane = tid & 63;
    const int w    = tid >> 6;           // wave 0..3
    const int cl   = lane & 31;          // this lane's x-row (D col)
    const int kh   = lane >> 5;          // k-half / code-half
    const int bmBase = blockIdx.x * 128; // 32 x-rows per wave
    const int myrow  = bmBase + w * 32 + cl;

// stage tile PAIR P (tiles 2P, 2P+1) into Bs[buf]: 8 gloads/thread
#define STAGE2(P_, buf) do { \
        int _P = (P_); \
        _Pragma("unroll") \
        for (int _i = 0; _i < 8; ++_i) { \
            int _half = _i >> 2; \
            int _f = (_i & 3) * 4 + w; \
            const short* _g = CBf + (size_t)(_P * 2 + _half) * 8192 \
                            + _f * 512 + lane * 8; \
            GLOAD_LDS(_g, &Bs[(buf)][_half * 8192 + _f * 512]); \
        } \
    } while (0)

    // cbn_f -> LDS (acc-order, all 4096 codes)
    #pragma unroll
    for (int j = 0; j < 4; ++j)
        *reinterpret_cast<float4*>(&cbn_fs[tid * 16 + j * 4]) =
            *reinterpret_cast<const float4*>(&cbn_f[tid * 16 + j * 4]);

    // X fragments (B-operand): af[kstep], lane holds x-row myrow,
    // k = kstep*16 + kh*8 .. +8
    bf16x8 af[16];
    {
        const short* ap = Xh + ((size_t)myrow << 8) + kh * 8;
        #pragma unroll
        for (int ks = 0; ks < 16; ++ks)
            af[ks] = *reinterpret_cast<const bf16x8*>(ap + ks * 16);
    }

    // lane-local threshold slack (exact per-row)
    float dlt, rmin = 1e30f;
    {
        float xr = xx[myrow];
        dlt = fmaf(0.003f, sqrtf(xr * __uint_as_float(*cbn_max)), 0.01f);
    }

    __syncthreads();            // cbn_fs visible; vmcnt drained to 0 (prologue)

    STAGE2(0, 0); STAGE2(1, 1);   // 16 issues/thread outstanding

    // 6 candidate slots (registers, static indexing): g=1e30 means empty
    float g0 = 1e30f, g1 = 1e30f, g2 = 1e30f, g3 = 1e30f, g4 = 1e30f, g5 = 1e30f;
    u32   s0 = 0,     s1 = 0,     s2 = 0,     s3 = 0,     s4 = 0,     s5 = 0;

// per-tile epilogue + candidate insert (register-only, 1 shfl)
#define EPI(accv, tile_) do { \
        int _t = (tile_); \
        float cbnv[16]; \
        _Pragma("unroll") \
        for (int _q = 0; _q < 4; ++_q) \
            *reinterpret_cast<float4*>(&cbnv[_q * 4]) = \
                *reinterpret_cast<const float4*>(&cbn_fs[_t * 32 + kh * 16 + _q * 4]); \
        float gv[16], _m = 1e30f; \
        _Pragma("unroll") \
        for (int _r = 0; _r < 16; ++_r) { \
            gv[_r] = fmaf(-2.f, (accv)[_r], cbnv[_r]); \
            _m = fminf(_m, gv[_r]); \
        } \
        _m = fminf(_m, __shfl_xor(_m, 32, 64)); \
        rmin = fminf(rmin, _m); \
        float _thr = rmin + dlt; \
        _Pragma("unroll") \
        for (int _r = 0; _r < 16; ++_r) { \
            if (gv[_r] <= _thr) { \
                u32 _code = (u32)(_t * 32 + (_r & 3) + 8 * (_r >> 2) + 4 * kh); \
                float _mg = g0; int _mi = 0; \
                if (g1 > _mg) { _mg = g1; _mi = 1; } \
                if (g2 > _mg) { _mg = g2; _mi = 2; } \
                if (g3 > _mg) { _mg = g3; _mi = 3; } \
                if (g4 > _mg) { _mg = g4; _mi = 4; } \
                if (g5 > _mg) { _mg = g5; _mi = 5; } \
                if (_mg > _thr) { \
                    if      (_mi == 0) { g0 = gv[_r]; s0 = _code; } \
                    else if (_mi == 1) { g1 = gv[_r]; s1 = _code; } \
                    else if (_mi == 2) { g2 = gv[_r]; s2 = _code; } \
                    else if (_mi == 3) { g3 = gv[_r]; s3 = _code; } \
                    else if (_mi == 4) { g4 = gv[_r]; s4 = _code; } \
                    else               { g5 = gv[_r]; s5 = _code; } \
                } else { \
                    exact_rerank(X, CB, xx, cbn, myrow, (int)_code, best); \
                } \
            } \
        } \
    } while (0)

    for (int s = 0; s < 64; ++s) {          // 64 steps x 2 tiles
        asm volatile("s_waitcnt vmcnt(8)" ::: "memory");
        __builtin_amdgcn_sched_barrier(0);
        __builtin_amdgcn_s_barrier();               // (A) buf[s&1] ready
        __builtin_amdgcn_sched_barrier(0);

        f32x16 aA, aB;
        #pragma unroll
        for (int r = 0; r < 16; ++r) { aA[r] = 0.f; aB[r] = 0.f; }

        const short* Bt = &Bs[s & 1][0];
        #pragma unroll
        for (int ks = 0; ks < 16; ++ks) {           // two independent chains
            bf16x8 cfA = *reinterpret_cast<const bf16x8*>(&Bt[ks * 512 + lane * 8]);
            bf16x8 cfB = *reinterpret_cast<const bf16x8*>(&Bt[8192 + ks * 512 + lane * 8]);
            aA = __builtin_amdgcn_mfma_f32_32x32x16_bf16(cfA, af[ks], aA, 0, 0, 0);
            aB = __builtin_amdgcn_mfma_f32_32x32x16_bf16(cfB, af[ks], aB, 0, 0, 0);
        }

        EPI(aA, s * 2);
        EPI(aB, s * 2 + 1);

        __builtin_amdgcn_sched_barrier(0);
        __builtin_amdgcn_s_barrier();               // (B) buf[s&1] free
        __builtin_amdgcn_sched_barrier(0);
        STAGE2((s + 2) & 63, s & 1);    // wrap keeps vmcnt count uniform
    }

    // post-loop: exact fp32 rerank of slots still within the FINAL window
    float thrF = rmin + dlt;
    if (g0 <= thrF) exact_rerank(X, CB, xx, cbn, myrow, (int)s0, best);
    if (g1 <= thrF) exact_rerank(X, CB, xx, cbn, myrow, (int)s1, best);
    if (g2 <= thrF) exact_rerank(X, CB, xx, cbn, myrow, (int)s2, best);
    if (g3 <= thrF) exact_rerank(X, CB, xx, cbn, myrow, (int)s3, best);
    if (g4 <= thrF) exact_rerank(X, CB, xx, cbn, myrow, (int)s4, best);
    if (g5 <= thrF) exact_rerank(X, CB, xx, cbn, myrow, (int)s5, best);
#undef EPI
#undef STAGE2
}

// ---------- kernel 3: gather e, Householder STE ----------
__global__ __launch_bounds__(256) void k_epilogue(const float* __restrict__ X,
                                                  const float* __restrict__ CB,
                                                  const u64* __restrict__ best,
                                                  float* __restrict__ Eout,
                                                  float* __restrict__ Sout) {
    int r    = blockIdx.x * 4 + (threadIdx.x >> 6);
    int lane = threadIdx.x & 63;
    int idx  = (int)(best[r] & 0xffffffffull);

    float4 xv = *reinterpret_cast<const float4*>(X  + (size_t)r   * COLS + lane * 4);
    float4 ev = *reinterpret_cast<const float4*>(CB + (size_t)idx * COLS + lane * 4);

    float xn2 = wave_sum(dot4(xv, xv));
    float en2 = wave_sum(dot4(ev, ev));
    float xn = sqrtf(xn2), en = sqrtf(en2);
    float invx = 1.f / fmaxf(xn, EPSF);
    float inve = 1.f / fmaxf(en, EPSF);

    float4 xd, ed, sd0;
    xd.x = xv.x*invx; xd.y = xv.y*invx; xd.z = xv.z*invx; xd.w = xv.w*invx;
    ed.x = ev.x*inve; ed.y = ev.y*inve; ed.z = ev.z*inve; ed.w = ev.w*inve;
    sd0.x = xd.x+ed.x; sd0.y = xd.y+ed.y; sd0.z = xd.z+ed.z; sd0.w = xd.w+ed.w;

    float sdn2 = wave_sum(dot4(sd0, sd0));
    float p1   = wave_sum(dot4(sd0, xv));
    float p2   = wave_sum(dot4(xd,  xv));
    float invs = 1.f / fmaxf(sqrtf(sdn2), EPSF);

    float csd = -2.f * invs * invs * p1;
    float ced =  2.f * p2;
    float4 rr;
    rr.x = fmaf(csd, sd0.x, fmaf(ced, ed.x, xv.x));
    rr.y = fmaf(csd, sd0.y, fmaf(ced, ed.y, xv.y));
    rr.z = fmaf(csd, sd0.z, fmaf(ced, ed.z, xv.z));
    rr.w = fmaf(csd, sd0.w, fmaf(ced, ed.w, xv.w));
    float sc = en * invx;
    float4 sv; sv.x = rr.x*sc; sv.y = rr.y*sc; sv.z = rr.z*sc; sv.w = rr.w*sc;

    *reinterpret_cast<float4*>(Eout + (size_t)r * COLS + lane * 4) = ev;
    *reinterpret_cast<float4*>(Sout + (size_t)r * COLS + lane * 4) = sv;
}

// ---------- launcher ----------
extern "C" void kernel_launch(void* const* d_in, const int* in_sizes, int n_in,
                              void* d_out, int out_size, void* d_ws, size_t ws_size,
                              hipStream_t stream) {
    const float* x  = (const float*)d_in[0];
    const float* fc = (const float*)d_in[1];
    const float* Wi = (const float*)d_in[2];
    const float* Wo = (const float*)d_in[3];

    // ws layout (~5 MB)
    char* ws = (char*)d_ws;
    u64*   best    = (u64*)ws;                            ws += (size_t)ROWS * 8;
    float* CBws    = (float*)ws;                          ws += (size_t)Nn * COLS * 4;
    float* cbn     = (float*)ws;                          ws += (size_t)Nn * 4;
    float* cbn_f   = (float*)ws;                          ws += (size_t)Nn * 4;
    float* xx      = (float*)ws;                          ws += (size_t)ROWS * 4;
    u32*   cbn_max = (u32*)ws;

    // bf16 copies live in d_out (128 MiB), only overwritten by k_epilogue at
    // the very end: Xh = 32 MiB at offset 0, CBf = 2 MiB at offset 64 MiB.
    short* Xh  = (short*)d_out;
    short* CBf = (short*)((char*)d_out + (64u << 20));

    float* Eout = (float*)d_out;
    float* Sout = Eout + (size_t)ROWS * COLS;

    k_prep<<<ROWS / 4, 256, 0, stream>>>(x, Xh, xx, best);
    k_codebook<<<Nn, 256, 0, stream>>>(fc, Wi, Wo, CBws, CBf, cbn, cbn_f);
    k_reduce_cbn<<<1, 256, 0, stream>>>(cbn, cbn_max);
    k_screen_fused<<<ROWS / 128, 256, 0, stream>>>(Xh, CBf, x, CBws, cbn, cbn_f,
                                                   xx, best, cbn_max);
    k_epilogue<<<ROWS / 4, 256, 0, stream>>>(x, CBws, best, Eout, Sout);
}